// Round 11
// baseline (48141.638 us; speedup 1.0000x reference)
//
#include <hip/hip_runtime.h>
#include <stdint.h>

#define T_STEPS 32768
#define I_DIM   256
#define H_DIM   1024
#define O_DIM   256
#define NWG     32     // persistent workgroups
#define ROWS    32     // h-rows owned per workgroup
#define NTHR    1024
#define NCHUNK  32     // column chunks per wg (32 cols each)
#define CPC     32     // Wh cols per thread
#define XPC     8      // Wx cols per thread

// h exchange buffer: hb[2][H_DIM] of {low32 = f32 value bits, high32 = step id}.
// Agent-scope atomics are serviced at the device coherence point (bypassing the
// non-coherent per-XCD L2s; they lower to global_load/store_dwordx2 with
// sc0/sc1 scope bits). An aligned 8B load is single-copy atomic, so the
// step-id validates the value in the SAME load: the successful poll IS the
// data read.
// Self-contained across replays: rnn_init arms BOTH slots every launch
// (slot1 = h_{-1}=0 @ id -1; slot0 = sentinel id 0xFFFFFFFE which matches no
// expected id), so correctness does not depend on the harness's 0xAA poison
// destroying stale packets from a previous replay (kills the t=32767 ABA:
// stale slot-0 id 32766 == that step's expect).
// Boundary algebra: t=0 polls slot (-1)&1 == 1 (C int semantics) with expect
// 0xFFFFFFFF — matches rnn_init's slot-1 arming; t=1 polls slot 0 with expect
// 0 — matches step-0's publish into slot 0&1 == 0.
// Slot-overwrite safety: publishing step t+1 into slot (t+1)&1 requires full
// validation of step t, which requires every wg already published step t,
// which requires every wave everywhere finished polling step t-1 — the slot
// being overwritten. No WAR race. WGs skew by at most 1 step -> no deadlock
// while all 32 WGs are resident (each 1024-thread WG = 16 waves = exactly one
// CU at 32-wave capacity; 32 WGs on 256 CUs = 8x headroom).

__global__ void rnn_init(unsigned long long* hb) {
    int i = blockIdx.x * 256 + threadIdx.x;
    if (i < H_DIM) {
        // slot 0: sentinel id 0xFFFFFFFE (matches no expect: -1, 0..32766)
        __hip_atomic_store(hb + i, 0xFFFFFFFE00000000ULL,
                           __ATOMIC_RELAXED, __HIP_MEMORY_SCOPE_AGENT);
        // slot 1: h_{-1} = 0.0f tagged with step id (unsigned)(-1)
        __hip_atomic_store(hb + H_DIM + i, 0xFFFFFFFF00000000ULL,
                           __ATOMIC_RELAXED, __HIP_MEMORY_SCOPE_AGENT);
    }
}

__global__ __launch_bounds__(NTHR) void rnn_scan(
    const float* __restrict__ x,    // [T][I]
    const float* __restrict__ Wx,   // [H][I]
    const float* __restrict__ Wh,   // [H][H]
    const float* __restrict__ bh,   // [H]
    float* __restrict__ out_hs,     // [H][T]
    unsigned long long* __restrict__ hb)  // [2][H]
{
    const int tid   = threadIdx.x;
    const int g     = blockIdx.x;
    const int row   = tid & 31;        // row within wg slice
    const int chunk = tid >> 5;        // 0..31, Wh cols [32*chunk, 32*chunk+32)
    const int grow  = g * ROWS + row;  // global h row
    const int w     = tid >> 6;        // wave id 0..15 (stages h[64w..64w+64))
    const int l     = tid & 63;

    // h_stage is wave-private: chunk = 2w + (l>>5), so each wave's dot reads
    // ONLY its own 64 staged values (2-address broadcast reads, conflict-free,
    // and no barrier needed between stage-write and dot).
    __shared__ float h_stage[16][64];
    __shared__ float x_lds[2][I_DIM];            // double-buffered x_t
    __shared__ float red[2][NCHUNK][ROWS + 1];   // partials; 2 lanes/bank = free

    // ---- weights into registers (one-time) ----
    float wh[CPC];
    {
        const float* wp = Wh + (size_t)grow * H_DIM + chunk * CPC;
#pragma unroll
        for (int j = 0; j < CPC; j += 4) {
            float4 v = *(const float4*)(wp + j);
            wh[j] = v.x; wh[j+1] = v.y; wh[j+2] = v.z; wh[j+3] = v.w;
        }
    }
    float wx[XPC];
    {
        const float* wp = Wx + (size_t)grow * I_DIM + chunk * XPC;
#pragma unroll
        for (int k = 0; k < XPC; k += 4) {
            float4 v = *(const float4*)(wp + k);
            wx[k] = v.x; wx[k+1] = v.y; wx[k+2] = v.z; wx[k+3] = v.w;
        }
    }
    float bh_r = 0.f;
    if (tid < ROWS) bh_r = bh[grow];

    // prologue: x[0] into x_lds[0]
    if (tid < I_DIM) x_lds[0][tid] = x[tid];
    __syncthreads();

    for (int t = 0; t < T_STEPS; ++t) {
        // issue next-step x load early (independent of the recurrence)
        float xn = 0.f;
        const bool xload = (tid < I_DIM) && (t + 1 < T_STEPS);
        if (xload) xn = x[(size_t)(t + 1) * I_DIM + tid];

        // ---- poll own h element; the successful poll IS the data read ----
        // Divergent loop: validated lanes drop out of exec, shrinking retry
        // traffic instead of re-gathering all 64 addresses per retry.
        const unsigned long long* hp =
            hb + (size_t)((t - 1) & 1) * H_DIM + tid;   // element index == tid
        const unsigned expect = (unsigned)(t - 1);
        unsigned long long v =
            __hip_atomic_load(hp, __ATOMIC_RELAXED, __HIP_MEMORY_SCOPE_AGENT);
        while ((unsigned)(v >> 32) != expect) {
            v = __hip_atomic_load(hp, __ATOMIC_RELAXED, __HIP_MEMORY_SCOPE_AGENT);
        }
        h_stage[w][l] = __uint_as_float((unsigned)v);

        // ---- partial dot: 32 Wh cols + 8 Wx cols ----
        const int base = (l >> 5) * 32;   // chunk-local base in wave staging
        float a0 = 0.f, a1 = 0.f, a2 = 0.f, a3 = 0.f;
#pragma unroll
        for (int j = 0; j < CPC; j += 4) {
            float4 h4 = *(const float4*)&h_stage[w][base + j];  // 2-addr bcast
            a0 = fmaf(wh[j],   h4.x, a0);
            a1 = fmaf(wh[j+1], h4.y, a1);
            a2 = fmaf(wh[j+2], h4.z, a2);
            a3 = fmaf(wh[j+3], h4.w, a3);
        }
        {
            const float* xp = &x_lds[t & 1][chunk * XPC];
            float4 xa = *(const float4*)(xp);
            float4 xb = *(const float4*)(xp + 4);
            a0 = fmaf(wx[0], xa.x, a0); a1 = fmaf(wx[1], xa.y, a1);
            a2 = fmaf(wx[2], xa.z, a2); a3 = fmaf(wx[3], xa.w, a3);
            a0 = fmaf(wx[4], xb.x, a0); a1 = fmaf(wx[5], xb.y, a1);
            a2 = fmaf(wx[6], xb.z, a2); a3 = fmaf(wx[7], xb.w, a3);
        }
        red[t & 1][chunk][row] = (a0 + a1) + (a2 + a3);

        if (xload) x_lds[(t + 1) & 1][tid] = xn;

        __syncthreads();

        // ---- reduce 32 partials/row with 2 threads/row, tanh, publish ----
        // Wave 0 races 15 polling waves for issue slots; boost it (T5: the
        // role-split exists — every other wg is waiting on THIS wave's store).
        if (tid < 2 * ROWS) {
            __builtin_amdgcn_s_setprio(1);
            const int r  = tid & 31;         // row
            const int cb = (tid >> 5) * 16;  // chunk base: 0 or 16
            float s0 = 0.f, s1 = 0.f, s2 = 0.f, s3 = 0.f;
#pragma unroll
            for (int c = 0; c < 16; c += 4) {
                s0 += red[t & 1][cb + c    ][r];
                s1 += red[t & 1][cb + c + 1][r];
                s2 += red[t & 1][cb + c + 2][r];
                s3 += red[t & 1][cb + c + 3][r];
            }
            float part = (s0 + s1) + (s2 + s3);
            part += __shfl_xor(part, 32, 64);   // combine the two half-sums
            if (tid < ROWS) {
                float pre = part + bh_r;
                // tanh(x) = 1 - 2/(exp(2x)+1): exact limits, ~ulp-level err
                float e  = __expf(2.f * pre);
                float hn = 1.f - 2.f / (e + 1.f);
                // publish FIRST (the store every other wg spins on), trace after
                unsigned long long pv =
                    ((unsigned long long)(unsigned)t << 32) |
                    (unsigned long long)__float_as_uint(hn);
                __hip_atomic_store(hb + (size_t)(t & 1) * H_DIM + grow, pv,
                                   __ATOMIC_RELAXED, __HIP_MEMORY_SCOPE_AGENT);
                out_hs[(size_t)grow * T_STEPS + t] = hn;  // write-combines over t
            }
            __builtin_amdgcn_s_setprio(0);
        }
    }
}

// y = Wy @ h_last + by. One wave per output row, 64 blocks x 4 waves:
// full-BW 1MB Wy read (~2us) instead of a single-block ~20us serial tail.
// No id-validation needed: kernel boundary on the stream orders rnn_scan's
// final publishes before these reads.
__global__ __launch_bounds__(256) void rnn_y(
    const float* __restrict__ Wy,   // [O][H]
    const float* __restrict__ by,   // [O]
    const unsigned long long* __restrict__ hb,
    float* __restrict__ y_out)      // [O]
{
    __shared__ float hsm[H_DIM];
    const int tid = threadIdx.x;
    for (int i = tid; i < H_DIM; i += 256) {
        unsigned long long v = __hip_atomic_load(
            hb + (size_t)((T_STEPS - 1) & 1) * H_DIM + i,
            __ATOMIC_RELAXED, __HIP_MEMORY_SCOPE_AGENT);
        hsm[i] = __uint_as_float((unsigned)v);
    }
    __syncthreads();
    const int o = blockIdx.x * 4 + (tid >> 6);  // output row, one per wave
    const int l = tid & 63;
    const float* wp = Wy + (size_t)o * H_DIM + l * 16;
    const float* hp = &hsm[l * 16];
    float s0 = 0.f, s1 = 0.f, s2 = 0.f, s3 = 0.f;
#pragma unroll
    for (int i = 0; i < 16; i += 4) {
        float4 wv = *(const float4*)(wp + i);
        s0 = fmaf(wv.x, hp[i],     s0);
        s1 = fmaf(wv.y, hp[i + 1], s1);
        s2 = fmaf(wv.z, hp[i + 2], s2);
        s3 = fmaf(wv.w, hp[i + 3], s3);
    }
    float s = (s0 + s1) + (s2 + s3);
#pragma unroll
    for (int m = 32; m >= 1; m >>= 1) s += __shfl_xor(s, m, 64);
    if (l == 0) y_out[o] = s + by[o];
}

extern "C" void kernel_launch(void* const* d_in, const int* in_sizes, int n_in,
                              void* d_out, int out_size, void* d_ws, size_t ws_size,
                              hipStream_t stream) {
    const float* x  = (const float*)d_in[0];
    const float* Wx = (const float*)d_in[1];
    const float* Wh = (const float*)d_in[2];
    const float* Wy = (const float*)d_in[3];
    const float* bh = (const float*)d_in[4];
    const float* by = (const float*)d_in[5];

    float* out_hs = (float*)d_out;                               // [H][T]
    float* y_out  = (float*)d_out + (size_t)H_DIM * T_STEPS;     // [O]
    unsigned long long* hb = (unsigned long long*)d_ws;          // 16 KiB used

    hipLaunchKernelGGL(rnn_init, dim3(4), dim3(256), 0, stream, hb);
    hipLaunchKernelGGL(rnn_scan, dim3(NWG), dim3(NTHR), 0, stream,
                       x, Wx, Wh, bh, out_hs, hb);
    hipLaunchKernelGGL(rnn_y, dim3(O_DIM / 4), dim3(256), 0, stream,
                       Wy, by, hb, y_out);
}